// Round 2
// baseline (481.526 us; speedup 1.0000x reference)
//
#include <hip/hip_runtime.h>
#include <hip/hip_bf16.h>

// Problem constants (from reference)
#define SCREEN_W 1280
#define SCREEN_H 720
#define TILE_L   16
#define NBW      80    // ceil(1280/16)
#define NBH      45    // ceil(720/16)
#define NUM_TILE 3600  // 80*45
#define N_POINTS 32768

typedef int v4i __attribute__((ext_vector_type(4)));

// ---------------------------------------------------------------------------
// R6: single fused kernel, global-item grid-stride.
//
// Work item g in [0, 3600*8192): tile = g>>13, uint4-group t = g&8191.
// Grid-stride = 2^19 (2048 blocks x 256 threads) so per thread:
//   - t is INVARIANT  -> compute the 4 points' tile ranges ONCE (no pk table,
//     no kernel A, one launch instead of two)
//   - tile = (blockIdx.x>>5) + 64*k  -> block-uniform, SALU xi/yi
// Each thread: 3 float4 loads (48 B, L2/L3-resident after first 64th) +
// ~40 VALU once, then 56-57 iterations of {4 range-compares, one 16 B store}.
// Store-BW-bound by construction: 472 MB coalesced streaming stores.
//
// Residency: 2048 blocks = exactly 8 blocks/CU (2048-thread cap), ONE full
// round, zero tail (R5's 7200-block config wasted ~14% in a half-empty last
// round). The 56-vs-57 iteration split covers blocks 0-511 = 2 blocks/CU,
// balanced across all CUs.
//
// Range semantics (verified absmax 0 in R4 and earlier):
//   overlap_x(xi) <=> (xmin>>4) <= xi < ((xmax+15)>>4), clamp/trunc identical
//   to reference.
// ---------------------------------------------------------------------------
__global__ void __launch_bounds__(256)
fused_mask_kernel(const float* __restrict__ pos2d,
                  const float* __restrict__ radius,
                  int* __restrict__ out) {
    const int lin = blockIdx.x * 256 + (int)threadIdx.x;  // [0, 2^19)
    const int t   = lin & 8191;                           // point-group, invariant
    const int n   = t * 4;                                // first point index

    // --- per-thread one-time: tile ranges for 4 points ---
    const float4 p01 = *(const float4*)(pos2d + 2 * n);       // x0 y0 x1 y1
    const float4 p23 = *(const float4*)(pos2d + 2 * n + 4);   // x2 y2 x3 y3
    const float4 r4  = *(const float4*)(radius + n);

    float xs[4] = {p01.x, p01.z, p23.x, p23.z};
    float ys[4] = {p01.y, p01.w, p23.y, p23.w};
    float rs[4] = {r4.x, r4.y, r4.z, r4.w};

    unsigned int xlo[4], xhi[4], ylo[4], yhi[4];
#pragma unroll
    for (int j = 0; j < 4; ++j) {
        float x = xs[j], y = ys[j], rr = rs[j];
        int xmin = (int)fminf(fmaxf(x - rr, 0.0f), (float)SCREEN_W);
        int ymin = (int)fminf(fmaxf(y - rr, 0.0f), (float)SCREEN_H);
        int xmax = (int)fminf(fmaxf(x + rr, 0.0f), (float)SCREEN_W);
        int ymax = (int)fminf(fmaxf(y + rr, 0.0f), (float)SCREEN_H);
        xlo[j] = (unsigned int)(xmin >> 4);
        xhi[j] = (unsigned int)((xmax + 15) >> 4);
        ylo[j] = (unsigned int)(ymin >> 4);
        yhi[j] = (unsigned int)((ymax + 15) >> 4);
    }

    // --- grid-stride over global items; tile steps by exactly 64 ---
    const int TOTAL  = NUM_TILE * (N_POINTS / 4);  // 29,491,200
    const int STRIDE = 2048 * 256;                 // 524,288 = 2^19

#pragma unroll 4
    for (int g = lin; g < TOTAL; g += STRIDE) {
        unsigned int tile = (unsigned int)g >> 13;       // block-uniform
        unsigned int xi = tile / (unsigned int)NBH;      // magic-mul
        unsigned int yi = tile - xi * (unsigned int)NBH;

        v4i res;
#pragma unroll
        for (int j = 0; j < 4; ++j) {
            res[j] = (xi >= xlo[j] && xi < xhi[j] &&
                      yi >= ylo[j] && yi < yhi[j]) ? 1 : 0;
        }

        // plain 16 B coalesced store (A/B'd vs nontemporal earlier; plain won)
        *(v4i*)(out + (size_t)g * 4) = res;
    }
}

extern "C" void kernel_launch(void* const* d_in, const int* in_sizes, int n_in,
                              void* d_out, int out_size, void* d_ws, size_t ws_size,
                              hipStream_t stream) {
    const float* pos2d  = (const float*)d_in[0];
    const float* radius = (const float*)d_in[1];
    int* out = (int*)d_out;

    // single launch: 2048 blocks x 256 threads, exactly 8 blocks/CU resident
    fused_mask_kernel<<<dim3(2048), dim3(256), 0, stream>>>(pos2d, radius, out);
}

// Round 3
// 461.001 us; speedup vs baseline: 1.0445x; 1.0445x over previous
//
#include <hip/hip_runtime.h>
#include <hip/hip_bf16.h>

// Problem constants (from reference)
#define SCREEN_W 1280
#define SCREEN_H 720
#define TILE_L   16
#define NBW      80    // ceil(1280/16)
#define NBH      45    // ceil(720/16)
#define NUM_TILE 3600  // 80*45
#define N_POINTS 32768

typedef int v4i __attribute__((ext_vector_type(4)));

// ---------------------------------------------------------------------------
// Kernel A (unchanged, verified absmax 0): per-point tile-index ranges packed
// into one u32: ximin | ximax<<8 | yimin<<16 | yimax<<24 (half-open ranges).
// overlap_x(tile xi) <=> (xmin>>4) <= xi < ((xmax+15)>>4)
// Table: 32768 * 4 B = 128 KB in d_ws.
// ---------------------------------------------------------------------------
__global__ void aabb_kernel(const float* __restrict__ pos2d,
                            const float* __restrict__ radius,
                            unsigned int* __restrict__ pk) {
    int t = blockIdx.x * blockDim.x + threadIdx.x;   // thread handles 4 points
    int n = t * 4;
    if (n >= N_POINTS) return;

    const float4* p4 = (const float4*)(pos2d + 2 * n);
    float4 p01 = p4[0];   // x0 y0 x1 y1
    float4 p23 = p4[1];   // x2 y2 x3 y3
    float4 r   = *(const float4*)(radius + n);

    float xs[4] = {p01.x, p01.z, p23.x, p23.z};
    float ys[4] = {p01.y, p01.w, p23.y, p23.w};
    float rs[4] = {r.x, r.y, r.z, r.w};

    uint4 outp;
    unsigned int* op = &outp.x;
#pragma unroll
    for (int j = 0; j < 4; ++j) {
        float x = xs[j], y = ys[j], rr = rs[j];
        int xmin = (int)fminf(fmaxf(x - rr, 0.0f), (float)SCREEN_W);
        int ymin = (int)fminf(fmaxf(y - rr, 0.0f), (float)SCREEN_H);
        int xmax = (int)fminf(fmaxf(x + rr, 0.0f), (float)SCREEN_W);
        int ymax = (int)fminf(fmaxf(y + rr, 0.0f), (float)SCREEN_H);
        unsigned int ximin = (unsigned int)(xmin >> 4);          // <= 80
        unsigned int ximax = (unsigned int)((xmax + 15) >> 4);   // <= 80
        unsigned int yimin = (unsigned int)(ymin >> 4);          // <= 45
        unsigned int yimax = (unsigned int)((ymax + 15) >> 4);   // <= 45
        op[j] = ximin | (ximax << 8) | (yimin << 16) | (yimax << 24);
    }
    *(uint4*)(pk + n) = outp;
}

// ---------------------------------------------------------------------------
// Kernel B (R7): ONE-SHOT store pattern preserved (empirically best: R4's
// 143 µs mask vs R5 163 / R6 178 — per-thread looping hurts monotonically),
// but block count cut 4x via 1024-thread blocks to test the dispatch-rate
// theory (R4: 115,200 blocks -> block lifetime ~6000 cyc vs ~500 cyc of
// work content; 28,800 blocks here).
//
// Grid: 28,800 blocks x 1024 threads = one thread per uint4 of output.
// Blocks are tile-aligned: 8192 uint4s per tile / 1024 = 8 blocks per tile,
//   tile = blockIdx.x >> 3        (wave-uniform -> SALU, incl. /45 magic)
//   t    = (blockIdx.x & 7)*1024 + threadIdx.x   (uint4 index within tile)
// Each thread: one uint4 pk load (L2-resident, 128 KB table), 4 byte-unpack
// compares, ONE plain coalesced 16 B store; block covers 16 KB contiguous.
// Occupancy: 16 waves/block, 2 blocks/CU = 32 waves/CU (full).
// ---------------------------------------------------------------------------
__global__ void __launch_bounds__(1024)
mask_kernel(const uint4* __restrict__ pk, int* __restrict__ out) {
    const unsigned int tile = blockIdx.x >> 3;                    // SALU
    const int t = (int)((blockIdx.x & 7u) << 10) + (int)threadIdx.x;

    const unsigned int xi = tile / (unsigned int)NBH;             // magic-mul
    const unsigned int yi = tile - xi * (unsigned int)NBH;

    uint4 p = pk[t];
    const unsigned int* pp = &p.x;

    v4i res;
#pragma unroll
    for (int j = 0; j < 4; ++j) {
        unsigned int w = pp[j];
        unsigned int ximin =  w        & 0xFFu;
        unsigned int ximax = (w >> 8)  & 0xFFu;
        unsigned int yimin = (w >> 16) & 0xFFu;
        unsigned int yimax =  w >> 24;
        res[j] = (xi >= ximin && xi < ximax && yi >= yimin && yi < yimax) ? 1 : 0;
    }

    // PLAIN coalesced 16 B store (A/B'd vs nontemporal in a prior session;
    // plain won). Output layout: out[tile * N_POINTS + n], tile-major [T, N].
    *(v4i*)(out + (size_t)tile * N_POINTS + 4 * t) = res;
}

extern "C" void kernel_launch(void* const* d_in, const int* in_sizes, int n_in,
                              void* d_out, int out_size, void* d_ws, size_t ws_size,
                              hipStream_t stream) {
    const float* pos2d  = (const float*)d_in[0];
    const float* radius = (const float*)d_in[1];
    int* out = (int*)d_out;
    unsigned int* pk = (unsigned int*)d_ws;   // 32768 * 4 B = 128 KB

    // Kernel A: 32768 points / 4 per thread = 8192 threads
    aabb_kernel<<<dim3(8192 / 256), dim3(256), 0, stream>>>(pos2d, radius, pk);

    // Kernel B: 3600 tiles * 8 blocks/tile = 28,800 blocks x 1024 threads
    mask_kernel<<<dim3(NUM_TILE * 8), dim3(1024), 0, stream>>>((const uint4*)pk, out);
}